// Round 1
// baseline (2065.415 us; speedup 1.0000x reference)
//
#include <hip/hip_runtime.h>
#include <hip/hip_bf16.h>

// Problem constants
#define M_DIM 512
#define HID 7168
#define D_KV_C 512
#define D_Q_C 1536
#define D_R 64
#define D_Q 128
#define D_KV 128
#define H_DIM 16
#define S_KV 4096
#define TOPK 512
#define D_ATT 576  // D_KV_C + D_R

// ---------------- Generic tiled fp32 GEMM (row-major) ----------------
// C[m*ldc + n] = sum_k A[m*lda + k] * B[k*ldb + n], batched via blockIdx.z
// Requires M%64==0, N%64==0, K%16==0 (true for all our shapes).
#define BM 64
#define BN 64
#define BK 16

__global__ __launch_bounds__(256) void gemm_f32(
    const float* __restrict__ A, int lda, int sA,
    const float* __restrict__ B, int ldb, int sB,
    float* __restrict__ C, int ldc, int sC,
    int K)
{
    int bz = blockIdx.z;
    A += bz * sA; B += bz * sB; C += bz * sC;
    int bm = blockIdx.y * BM, bn = blockIdx.x * BN;

    __shared__ float As[BK][BM + 4];  // pad 4 floats: 16B-aligned rows, ~2-way banks
    __shared__ float Bs[BK][BN + 4];

    int tid = threadIdx.x;
    int tx = tid & 15, ty = tid >> 4;

    float acc[4][4] = {};

    for (int k0 = 0; k0 < K; k0 += BK) {
        // A tile: As[k][m] = A[(bm+m)*lda + k0+k]; 16 lanes read 16 consecutive k
        #pragma unroll
        for (int i = 0; i < 4; i++) {
            int idx = tid + i * 256;      // 0..1023
            int m = idx >> 4;
            int k = idx & 15;
            As[k][m] = A[(bm + m) * lda + k0 + k];
        }
        // B tile: Bs[k][n] = B[(k0+k)*ldb + bn+n]; 64 lanes read 64 consecutive n
        #pragma unroll
        for (int i = 0; i < 4; i++) {
            int idx = tid + i * 256;
            int k = idx >> 6;
            int n = idx & 63;
            Bs[k][n] = B[(k0 + k) * ldb + bn + n];
        }
        __syncthreads();

        #pragma unroll
        for (int k = 0; k < BK; k++) {
            float a[4], b[4];
            #pragma unroll
            for (int i = 0; i < 4; i++) a[i] = As[k][ty * 4 + i];
            #pragma unroll
            for (int j = 0; j < 4; j++) b[j] = Bs[k][tx * 4 + j];
            #pragma unroll
            for (int i = 0; i < 4; i++)
                #pragma unroll
                for (int j = 0; j < 4; j++)
                    acc[i][j] += a[i] * b[j];
        }
        __syncthreads();
    }

    #pragma unroll
    for (int i = 0; i < 4; i++) {
        int row = bm + ty * 4 + i;
        #pragma unroll
        for (int j = 0; j < 4; j++)
            C[row * ldc + bn + tx * 4 + j] = acc[i][j];
    }
}

// ---------------- copy q_pe into q_full tail ----------------
__global__ void copy_pe(const float* __restrict__ q, float* __restrict__ q_full)
{
    int i = blockIdx.x * 256 + threadIdx.x;   // total M*H*D_R = 524288
    if (i >= M_DIM * H_DIM * D_R) return;
    int r = i & 63, mh = i >> 6;
    q_full[mh * D_ATT + D_KV_C + r] = q[mh * (D_Q + D_R) + D_Q + r];
}

// ---------------- fused attention: scores -> softmax -> PV ----------------
// grid = M blocks, 256 threads. kv_cache (9.4 MB) is L2-resident; read direct.
__global__ __launch_bounds__(256) void attn_kernel(
    const float* __restrict__ q_full,    // (M, H, 576)
    const float* __restrict__ kv_cache,  // (4096, 576)
    const int*   __restrict__ indices,   // (M, 512)
    float* __restrict__ o)               // (M, H, 512)
{
    int m = blockIdx.x;
    int tid = threadIdx.x;

    __shared__ float q_s[H_DIM * 580];   // stride 580: 16B aligned, spread banks
    __shared__ float s_s[H_DIM * 516];   // scores, stride 516: ~2-way banks
    __shared__ int   idx_s[TOPK];

    // stage q_full row (16x576) as float4
    const float4* qg = (const float4*)(q_full + (size_t)m * (H_DIM * D_ATT));
    for (int i = tid; i < H_DIM * (D_ATT / 4); i += 256) {
        int hh = i / (D_ATT / 4), d4 = i % (D_ATT / 4);
        *(float4*)&q_s[hh * 580 + d4 * 4] = qg[hh * (D_ATT / 4) + d4];
    }
    for (int i = tid; i < TOPK; i += 256) idx_s[i] = indices[m * TOPK + i];
    __syncthreads();

    const float scale = 1.0f / 24.0f;  // 1/sqrt(576)

    // ---- scores: thread (h = tid&15, tt = tid>>4) ----
    {
        int h = tid & 15, tt = tid >> 4;
        const float4* qrow = (const float4*)&q_s[h * 580];
        for (int t = tt; t < TOPK; t += 16) {
            const float4* row = (const float4*)(kv_cache + (size_t)idx_s[t] * D_ATT);
            float acc = 0.f;
            #pragma unroll 4
            for (int d = 0; d < D_ATT / 4; d++) {
                float4 a = qrow[d];
                float4 b = row[d];
                acc += a.x * b.x + a.y * b.y + a.z * b.z + a.w * b.w;
            }
            s_s[h * 516 + t] = acc * scale;
        }
    }
    __syncthreads();

    // ---- softmax per head row: h = tid>>4, 16 lanes per row ----
    {
        int h = tid >> 4, j = tid & 15;
        float mx = -1e30f;
        for (int t = j; t < TOPK; t += 16) mx = fmaxf(mx, s_s[h * 516 + t]);
        #pragma unroll
        for (int off = 8; off; off >>= 1) mx = fmaxf(mx, __shfl_xor(mx, off, 16));
        float sum = 0.f;
        for (int t = j; t < TOPK; t += 16) {
            float e = __expf(s_s[h * 516 + t] - mx);
            s_s[h * 516 + t] = e;
            sum += e;
        }
        #pragma unroll
        for (int off = 8; off; off >>= 1) sum += __shfl_xor(sum, off, 16);
        float inv = 1.0f / sum;
        for (int t = j; t < TOPK; t += 16) s_s[h * 516 + t] *= inv;
    }
    __syncthreads();

    // ---- PV: thread (h = tid>>4, cg = tid&15) owns 32 output cols ----
    {
        int h = tid >> 4, cg = tid & 15;
        float acc[32] = {};
        for (int t = 0; t < TOPK; t++) {
            float w = s_s[h * 516 + t];
            const float4* row = (const float4*)(kv_cache + (size_t)idx_s[t] * D_ATT) + cg * 8;
            #pragma unroll
            for (int v = 0; v < 8; v++) {
                float4 b = row[v];
                acc[v * 4 + 0] += w * b.x;
                acc[v * 4 + 1] += w * b.y;
                acc[v * 4 + 2] += w * b.z;
                acc[v * 4 + 3] += w * b.w;
            }
        }
        float* orow = o + (size_t)m * (H_DIM * D_KV_C) + h * D_KV_C + cg * 32;
        #pragma unroll
        for (int v = 0; v < 8; v++)
            *(float4*)&orow[v * 4] = make_float4(acc[v * 4], acc[v * 4 + 1], acc[v * 4 + 2], acc[v * 4 + 3]);
    }
}

// ---------------- launch ----------------
extern "C" void kernel_launch(void* const* d_in, const int* in_sizes, int n_in,
                              void* d_out, int out_size, void* d_ws, size_t ws_size,
                              hipStream_t stream)
{
    const float* x        = (const float*)d_in[0];  // (512, 7168)
    const float* W_cqkv   = (const float*)d_in[1];  // (7168, 2112)
    const float* W_uq     = (const float*)d_in[2];  // (1536, 3072)
    const float* W_qk     = (const float*)d_in[3];  // (16, 128, 512)
    const float* kv_cache = (const float*)d_in[4];  // (4096, 576)
    const float* W_o1     = (const float*)d_in[5];  // (16, 512, 128)
    const float* W_oproj  = (const float*)d_in[6];  // (2048, 7168)
    const int*   indices  = (const int*)d_in[7];    // (512, 512)
    float* out = (float*)d_out;                     // (512, 7168)

    // workspace layout (floats)
    float* ws = (float*)d_ws;
    float* q_c    = ws;                       // 512*1536   =  786432
    float* q      = q_c    + 786432;          // 512*3072   = 1572864
    float* q_full = q      + 1572864;         // 512*16*576 = 4718592
    float* o      = q_full + 4718592;         // 512*16*512 = 4194304
    float* o2     = o      + 4194304;         // 512*2048   = 1048576
    // total ~47 MB

    // 1) q_c = x @ W_cqkv[:, 512:2048]   (skip unused kv_c_new and rope-tail cols)
    gemm_f32<<<dim3(D_Q_C / BN, M_DIM / BM, 1), 256, 0, stream>>>(
        x, HID, 0, W_cqkv + D_KV_C, D_KV_C + D_Q_C + D_R, 0, q_c, D_Q_C, 0, HID);

    // 2) q = q_c @ W_uq  -> (512, 16*192)
    gemm_f32<<<dim3((H_DIM * (D_Q + D_R)) / BN, M_DIM / BM, 1), 256, 0, stream>>>(
        q_c, D_Q_C, 0, W_uq, H_DIM * (D_Q + D_R), 0, q, H_DIM * (D_Q + D_R), 0, D_Q_C);

    // 2b) copy q_pe tail into q_full
    copy_pe<<<(M_DIM * H_DIM * D_R + 255) / 256, 256, 0, stream>>>(q, q_full);

    // 3) q_abs[h] = q_nope[:,h,:] @ W_qk[h]  -> q_full[:, h, :512]  (batched, z=h)
    gemm_f32<<<dim3(D_KV_C / BN, M_DIM / BM, H_DIM), 256, 0, stream>>>(
        q, H_DIM * (D_Q + D_R), (D_Q + D_R),
        W_qk, D_KV_C, D_Q * D_KV_C,
        q_full, H_DIM * D_ATT, D_ATT, D_Q);

    // 4) fused attention
    attn_kernel<<<M_DIM, 256, 0, stream>>>(q_full, kv_cache, indices, o);

    // 5) o2[h] = o[:,h,:] @ W_o1[h]  (batched, z=h)
    gemm_f32<<<dim3(D_KV / BN, M_DIM / BM, H_DIM), 256, 0, stream>>>(
        o, H_DIM * D_KV_C, D_KV_C,
        W_o1, D_KV, D_KV_C * D_KV,
        o2, H_DIM * D_KV, D_KV, D_KV_C);

    // 6) out = o2 @ W_oproj
    gemm_f32<<<dim3(HID / BN, M_DIM / BM, 1), 256, 0, stream>>>(
        o2, H_DIM * D_KV, 0, W_oproj, HID, 0, out, HID, 0, H_DIM * D_KV);
}

// Round 2
// 1076.698 us; speedup vs baseline: 1.9183x; 1.9183x over previous
//
#include <hip/hip_runtime.h>
#include <hip/hip_bf16.h>

#define M_DIM 512
#define HID 7168
#define D_KV_C 512
#define D_Q_C 1536
#define D_R 64
#define D_Q 128
#define D_KV 128
#define H_DIM 16
#define S_KV 4096
#define TOPK 512
#define D_ATT 576

typedef __attribute__((ext_vector_type(8))) short bf16x8_t;
typedef __attribute__((ext_vector_type(4))) float f32x4_t;
typedef __attribute__((ext_vector_type(2))) unsigned int u32x2_t;

#define MFMA16(a, b, c) __builtin_amdgcn_mfma_f32_16x16x32_bf16((a), (b), (c), 0, 0, 0)

__device__ __forceinline__ unsigned short f2bf(float f) {
    union { float f; unsigned u; } v; v.f = f;
    unsigned r = v.u + 0x7FFFu + ((v.u >> 16) & 1u);
    return (unsigned short)(r >> 16);
}
__device__ __forceinline__ float bf2f(unsigned short b) {
    union { unsigned u; float f; } v; v.u = ((unsigned)b) << 16;
    return v.f;
}
__device__ __forceinline__ unsigned lds_addr32(const void* p) {
    return (unsigned)(unsigned long long)(const __attribute__((address_space(3))) char*)p;
}

// ---------------- Generic tiled fp32 GEMM (unchanged from R1) ----------------
#define BM 64
#define BN 64
#define BK 16

__global__ __launch_bounds__(256) void gemm_f32(
    const float* __restrict__ A, int lda, int sA,
    const float* __restrict__ B, int ldb, int sB,
    float* __restrict__ C, int ldc, int sC,
    int K)
{
    int bz = blockIdx.z;
    A += bz * (size_t)sA; B += bz * (size_t)sB; C += bz * (size_t)sC;
    int bm = blockIdx.y * BM, bn = blockIdx.x * BN;

    __shared__ float As[BK][BM + 4];
    __shared__ float Bs[BK][BN + 4];

    int tid = threadIdx.x;
    int tx = tid & 15, ty = tid >> 4;

    float acc[4][4] = {};

    for (int k0 = 0; k0 < K; k0 += BK) {
        #pragma unroll
        for (int i = 0; i < 4; i++) {
            int idx = tid + i * 256;
            int m = idx >> 4;
            int k = idx & 15;
            As[k][m] = A[(size_t)(bm + m) * lda + k0 + k];
        }
        #pragma unroll
        for (int i = 0; i < 4; i++) {
            int idx = tid + i * 256;
            int k = idx >> 6;
            int n = idx & 63;
            Bs[k][n] = B[(size_t)(k0 + k) * ldb + bn + n];
        }
        __syncthreads();

        #pragma unroll
        for (int k = 0; k < BK; k++) {
            float a[4], b[4];
            #pragma unroll
            for (int i = 0; i < 4; i++) a[i] = As[k][ty * 4 + i];
            #pragma unroll
            for (int j = 0; j < 4; j++) b[j] = Bs[k][tx * 4 + j];
            #pragma unroll
            for (int i = 0; i < 4; i++)
                #pragma unroll
                for (int j = 0; j < 4; j++)
                    acc[i][j] += a[i] * b[j];
        }
        __syncthreads();
    }

    #pragma unroll
    for (int i = 0; i < 4; i++) {
        int row = bm + ty * 4 + i;
        #pragma unroll
        for (int j = 0; j < 4; j++)
            C[(size_t)row * ldc + bn + tx * 4 + j] = acc[i][j];
    }
}

// ---------------- copy q_pe into q_full tail ----------------
__global__ void copy_pe(const float* __restrict__ q, float* __restrict__ q_full)
{
    int i = blockIdx.x * 256 + threadIdx.x;
    if (i >= M_DIM * H_DIM * D_R) return;
    int r = i & 63, mh = i >> 6;
    q_full[(size_t)mh * D_ATT + D_KV_C + r] = q[(size_t)mh * (D_Q + D_R) + D_Q + r];
}

// ---------------- fp32 -> bf16 converters ----------------
__global__ void cvt_kv_kernel(const float* __restrict__ src, unsigned short* __restrict__ dst, int n8)
{
    int i = blockIdx.x * 256 + threadIdx.x;
    if (i >= n8) return;
    const float4* s = (const float4*)src + (size_t)i * 2;
    float4 a = s[0], b = s[1];
    float v[8] = {a.x, a.y, a.z, a.w, b.x, b.y, b.z, b.w};
    union { bf16x8_t s8; unsigned short u[8]; } o;
    #pragma unroll
    for (int j = 0; j < 8; j++) o.u[j] = f2bf(v[j]);
    *(bf16x8_t*)(dst + (size_t)i * 8) = o.s8;
}

__global__ void cvt_q_kernel(const float* __restrict__ src,
                             unsigned short* __restrict__ hi,
                             unsigned short* __restrict__ lo, int n8)
{
    int i = blockIdx.x * 256 + threadIdx.x;
    if (i >= n8) return;
    const float4* s = (const float4*)src + (size_t)i * 2;
    float4 a = s[0], b = s[1];
    float v[8] = {a.x, a.y, a.z, a.w, b.x, b.y, b.z, b.w};
    union { bf16x8_t s8; unsigned short u[8]; } oh, ol;
    #pragma unroll
    for (int j = 0; j < 8; j++) {
        unsigned short hb = f2bf(v[j]);
        oh.u[j] = hb;
        ol.u[j] = f2bf(v[j] - bf2f(hb));
    }
    *(bf16x8_t*)(hi + (size_t)i * 8) = oh.s8;
    *(bf16x8_t*)(lo + (size_t)i * 8) = ol.s8;
}

// ---------------- MFMA attention ----------------
// grid = M blocks, 256 threads (4 waves). Per block: one query row m.
// scores: S(16h x 512t) = Qhi/Qlo(16x576) x KV^T  via 16x16x32 MFMA, B-frags direct from global bf16 kv.
// softmax fp32 in LDS; P emitted bf16 (xor-swizzled rows).
// PV: o(16h x 512c) = P x V, V staged per 32-row tile in xor-swizzled LDS, B-frags via ds_read_b64_tr_b16.
__global__ __launch_bounds__(256) void attn_mfma(
    const unsigned short* __restrict__ qhi,   // [M*16][576] bf16 bits
    const unsigned short* __restrict__ qlo,
    const unsigned short* __restrict__ kvb,   // [4096][576] bf16 bits
    const int* __restrict__ indices,          // [M][512]
    float* __restrict__ o)                    // [M][16][512]
{
    const int m = blockIdx.x;
    const int tid = threadIdx.x;
    const int w = tid >> 6, lane = tid & 63;
    const int l15 = lane & 15, q = lane >> 4;

    __shared__ __align__(16) char u_mem[16 * 513 * 4];         // scores f32 [16][513]  /  V-tile swizzled [32][1024B]
    __shared__ __align__(16) unsigned short p_s[16 * 512];     // P bf16, xor-swizzled rows of 1024B
    __shared__ int idx_s[TOPK];

    float* s_s = (float*)u_mem;
    unsigned short* v_s = (unsigned short*)u_mem;

    for (int i = tid; i < TOPK; i += 256) idx_s[i] = indices[(size_t)m * TOPK + i];
    __syncthreads();

    // ---------- scores ----------
    int rows[8];
    #pragma unroll
    for (int tt = 0; tt < 8; tt++) rows[tt] = idx_s[(w * 8 + tt) * 16 + l15];

    f32x4_t acc[8];
    #pragma unroll
    for (int tt = 0; tt < 8; tt++) acc[tt] = (f32x4_t){0.f, 0.f, 0.f, 0.f};

    const unsigned short* qh = qhi + ((size_t)m * 16 + l15) * D_ATT + q * 8;
    const unsigned short* ql = qlo + ((size_t)m * 16 + l15) * D_ATT + q * 8;

    #pragma unroll 2
    for (int kk = 0; kk < 18; kk++) {
        bf16x8_t ah = *(const bf16x8_t*)(qh + kk * 32);
        bf16x8_t al = *(const bf16x8_t*)(ql + kk * 32);
        #pragma unroll
        for (int tt = 0; tt < 8; tt++) {
            bf16x8_t b = *(const bf16x8_t*)(kvb + (size_t)rows[tt] * D_ATT + kk * 32 + q * 8);
            acc[tt] = MFMA16(al, b, acc[tt]);
            acc[tt] = MFMA16(ah, b, acc[tt]);
        }
    }

    const float scale = 1.0f / 24.0f;
    #pragma unroll
    for (int tt = 0; tt < 8; tt++) {
        int t = (w * 8 + tt) * 16 + l15;
        #pragma unroll
        for (int r = 0; r < 4; r++)
            s_s[(q * 4 + r) * 513 + t] = acc[tt][r] * scale;
    }
    __syncthreads();

    // ---------- softmax (fp32), emit P bf16 swizzled ----------
    {
        int h = tid >> 4, j = tid & 15;
        float mx = -1e30f;
        for (int t = j; t < TOPK; t += 16) mx = fmaxf(mx, s_s[h * 513 + t]);
        #pragma unroll
        for (int off = 8; off; off >>= 1) mx = fmaxf(mx, __shfl_xor(mx, off, 16));
        float sum = 0.f;
        for (int t = j; t < TOPK; t += 16) {
            float e = __expf(s_s[h * 513 + t] - mx);
            s_s[h * 513 + t] = e;
            sum += e;
        }
        #pragma unroll
        for (int off = 8; off; off >>= 1) sum += __shfl_xor(sum, off, 16);
        float inv = 1.0f / sum;
        for (int t = j; t < TOPK; t += 16) {
            unsigned short pb = f2bf(s_s[h * 513 + t] * inv);
            unsigned byte = ((unsigned)(t * 2)) ^ (((unsigned)(h & 7)) << 4);
            p_s[h * 512 + (byte >> 1)] = pb;
        }
    }
    __syncthreads();

    // ---------- PV ----------
    f32x4_t oacc[8];
    #pragma unroll
    for (int i = 0; i < 8; i++) oacc[i] = (f32x4_t){0.f, 0.f, 0.f, 0.f};

    const unsigned vbase = lds_addr32(v_s);
    const int jb = tid & 7, trow = tid >> 3;                   // staging: 32 rows x 8 col-blocks
    const unsigned swz_w = (((unsigned)(trow & 7)) << 4) ^ (((unsigned)((trow >> 3) & 3)) << 5);

    const int row1 = q * 8 + (l15 >> 2);
    const int row2 = row1 + 4;
    const unsigned sw1 = (((unsigned)(row1 & 7)) << 4) ^ (((unsigned)q & 3u) << 5);
    const unsigned sw2 = (((unsigned)(row2 & 7)) << 4) ^ (((unsigned)q & 3u) << 5);
    const unsigned cbyte = (unsigned)((l15 & 3) * 8);

    #pragma unroll 1
    for (int ct = 0; ct < 16; ct++) {
        int t0 = ct * 32;
        // stage V tile: rows t0..t0+31, cols 0..511, bf16, xor-swizzled within 1024B rows
        {
            int r = idx_s[t0 + trow];
            const unsigned short* src = kvb + (size_t)r * D_ATT + jb * 64;
            #pragma unroll
            for (int i = 0; i < 8; i++) {
                unsigned byte = ((unsigned)(jb * 128 + i * 16)) ^ swz_w;
                *(bf16x8_t*)((char*)v_s + trow * 1024 + byte) = *(const bf16x8_t*)(src + i * 8);
            }
        }
        __syncthreads();

        // A-frag: P[h = l15][t0 + q*8 .. +7] from swizzled p_s
        bf16x8_t pa;
        {
            unsigned pbyte = ((unsigned)(t0 * 2 + q * 16)) ^ (((unsigned)(l15 & 7)) << 4);
            pa = *(const bf16x8_t*)((const char*)p_s + l15 * 1024 + pbyte);
        }

        // B-frags via hardware transpose reads
        u32x2_t blo[8], bhi[8];
        #pragma unroll
        for (int i = 0; i < 8; i++) {
            unsigned c2 = ((unsigned)(((w * 8 + i) * 16) * 2)) + cbyte;
            unsigned a1 = vbase + (unsigned)row1 * 1024u + (c2 ^ sw1);
            unsigned a2 = vbase + (unsigned)row2 * 1024u + (c2 ^ sw2);
            asm volatile("ds_read_b64_tr_b16 %0, %1 offset:0" : "=v"(blo[i]) : "v"(a1) : "memory");
            asm volatile("ds_read_b64_tr_b16 %0, %1 offset:0" : "=v"(bhi[i]) : "v"(a2) : "memory");
        }
        asm volatile("s_waitcnt lgkmcnt(0)" ::: "memory");
        __builtin_amdgcn_sched_barrier(0);

        #pragma unroll
        for (int i = 0; i < 8; i++) {
            union { bf16x8_t s; struct { u32x2_t lo, hi; } u; } f;
            f.u.lo = blo[i]; f.u.hi = bhi[i];
            oacc[i] = MFMA16(pa, f.s, oacc[i]);
        }
        __syncthreads();
    }

    // write o (fp32)
    float* ob = o + (size_t)m * (H_DIM * D_KV_C);
    #pragma unroll
    for (int i = 0; i < 8; i++) {
        int c = (w * 8 + i) * 16 + l15;
        #pragma unroll
        for (int r = 0; r < 4; r++)
            ob[(size_t)(q * 4 + r) * D_KV_C + c] = oacc[i][r];
    }
}

// ---------------- launch ----------------
extern "C" void kernel_launch(void* const* d_in, const int* in_sizes, int n_in,
                              void* d_out, int out_size, void* d_ws, size_t ws_size,
                              hipStream_t stream)
{
    const float* x        = (const float*)d_in[0];
    const float* W_cqkv   = (const float*)d_in[1];
    const float* W_uq     = (const float*)d_in[2];
    const float* W_qk     = (const float*)d_in[3];
    const float* kv_cache = (const float*)d_in[4];
    const float* W_o1     = (const float*)d_in[5];
    const float* W_oproj  = (const float*)d_in[6];
    const int*   indices  = (const int*)d_in[7];
    float* out = (float*)d_out;

    // workspace layout (with overlays; all regions 16B aligned)
    float* ws = (float*)d_ws;
    float* q_c    = ws;                        // [0, 786432)           512*1536
    float* q      = ws + 786432;               // [786432, 2359296)     512*3072
    float* q_full = ws + 2359296;              // [2359296, 7077888)    512*16*576
    float* o      = q_full;                    // overlay: q_full dead after cvt_q; 512*16*512 fits
    float* o2     = q;                         // overlay: q dead after cvt_q; 512*2048 fits
    unsigned short* qhi = (unsigned short*)(ws + 7077888);           // 4718592 bf16
    unsigned short* qlo = qhi + 4718592;                             // 4718592 bf16
    unsigned short* kvb = qlo + 4718592;                             // 2359296 bf16

    // 0) kv -> bf16 (independent)
    cvt_kv_kernel<<<(S_KV * D_ATT / 8 + 255) / 256, 256, 0, stream>>>(
        kv_cache, kvb, S_KV * D_ATT / 8);

    // 1) q_c = x @ W_cqkv[:, 512:2048]
    gemm_f32<<<dim3(D_Q_C / BN, M_DIM / BM, 1), 256, 0, stream>>>(
        x, HID, 0, W_cqkv + D_KV_C, D_KV_C + D_Q_C + D_R, 0, q_c, D_Q_C, 0, HID);

    // 2) q = q_c @ W_uq
    gemm_f32<<<dim3((H_DIM * (D_Q + D_R)) / BN, M_DIM / BM, 1), 256, 0, stream>>>(
        q_c, D_Q_C, 0, W_uq, H_DIM * (D_Q + D_R), 0, q, H_DIM * (D_Q + D_R), 0, D_Q_C);

    // 2b) q_pe tail into q_full
    copy_pe<<<(M_DIM * H_DIM * D_R + 255) / 256, 256, 0, stream>>>(q, q_full);

    // 3) q_abs[h] = q_nope[:,h,:] @ W_qk[h] -> q_full[:, h, :512]
    gemm_f32<<<dim3(D_KV_C / BN, M_DIM / BM, H_DIM), 256, 0, stream>>>(
        q, H_DIM * (D_Q + D_R), (D_Q + D_R),
        W_qk, D_KV_C, D_Q * D_KV_C,
        q_full, H_DIM * D_ATT, D_ATT, D_Q);

    // 3b) q_full -> bf16 hi/lo
    cvt_q_kernel<<<(M_DIM * H_DIM * D_ATT / 8 + 255) / 256, 256, 0, stream>>>(
        q_full, qhi, qlo, M_DIM * H_DIM * D_ATT / 8);

    // 4) fused MFMA attention
    attn_mfma<<<M_DIM, 256, 0, stream>>>(qhi, qlo, kvb, indices, o);

    // 5) o2[h] = o[:,h,:] @ W_o1[h]
    gemm_f32<<<dim3(D_KV / BN, M_DIM / BM, H_DIM), 256, 0, stream>>>(
        o, H_DIM * D_KV_C, D_KV_C,
        W_o1, D_KV, D_KV_C * D_KV,
        o2, H_DIM * D_KV, D_KV, D_KV_C);

    // 6) out = o2 @ W_oproj
    gemm_f32<<<dim3(HID / BN, M_DIM / BM, 1), 256, 0, stream>>>(
        o2, H_DIM * D_KV, 0, W_oproj, HID, 0, out, HID, 0, H_DIM * D_KV);
}

// Round 3
// 261.432 us; speedup vs baseline: 7.9004x; 4.1185x over previous
//
#include <hip/hip_runtime.h>
#include <hip/hip_bf16.h>

#define M_DIM 512
#define HID 7168
#define D_KV_C 512
#define D_Q_C 1536
#define D_R 64
#define D_Q 128
#define D_KV 128
#define H_DIM 16
#define S_KV 4096
#define TOPK 512
#define D_ATT 576

typedef _Float16 half_t;
typedef __attribute__((ext_vector_type(8))) _Float16 f16x8_t;
typedef __attribute__((ext_vector_type(4))) float f32x4_t;
typedef __attribute__((ext_vector_type(2))) unsigned int u32x2_t;

#define MFMA_F16(a, b, c) __builtin_amdgcn_mfma_f32_16x16x32_f16((a), (b), (c), 0, 0, 0)

__device__ __forceinline__ unsigned lds_addr32(const void* p) {
    return (unsigned)(unsigned long long)(const __attribute__((address_space(3))) char*)p;
}

typedef const __attribute__((address_space(1))) unsigned int* gptr_t;
typedef __attribute__((address_space(3))) unsigned int* lptr_t;
__device__ __forceinline__ void gload_lds16(const void* g, void* l) {
    __builtin_amdgcn_global_load_lds((gptr_t)g, (lptr_t)l, 16, 0, 0);
}

// ---------------- elementwise fp32 -> fp16 ----------------
__global__ __launch_bounds__(256) void cvt_f16(const float* __restrict__ src,
                                               half_t* __restrict__ dst, int n8)
{
    int i = blockIdx.x * 256 + threadIdx.x;
    if (i >= n8) return;
    const float4* s = (const float4*)src + (size_t)i * 2;
    float4 a = s[0], b = s[1];
    f16x8_t o;
    o[0] = (half_t)a.x; o[1] = (half_t)a.y; o[2] = (half_t)a.z; o[3] = (half_t)a.w;
    o[4] = (half_t)b.x; o[5] = (half_t)b.y; o[6] = (half_t)b.z; o[7] = (half_t)b.w;
    *(f16x8_t*)(dst + (size_t)i * 8) = o;
}

// ---------------- transpose-convert fp32 [K][ld] -> fp16 [N][K] ----------------
// tile 64x64; grid (N/64, K/64, Z)
__global__ __launch_bounds__(256) void cvt_t(
    const float* __restrict__ src, int ld_src, long long sS,
    half_t* __restrict__ dst, int ld_dst, long long sD)
{
    src += (size_t)blockIdx.z * sS;
    dst += (size_t)blockIdx.z * sD;
    int k0 = blockIdx.y * 64, n0 = blockIdx.x * 64;
    __shared__ half_t t[64][80];   // [n][k], row 160B (16B-aligned)
    int tid = threadIdx.x;
    int kr = tid >> 4, nc = (tid & 15) * 4;
    #pragma unroll
    for (int i = 0; i < 4; i++) {
        float4 v = *(const float4*)&src[(size_t)(k0 + kr + i * 16) * ld_src + n0 + nc];
        t[nc + 0][kr + i * 16] = (half_t)v.x;
        t[nc + 1][kr + i * 16] = (half_t)v.y;
        t[nc + 2][kr + i * 16] = (half_t)v.z;
        t[nc + 3][kr + i * 16] = (half_t)v.w;
    }
    __syncthreads();
    int nr = tid >> 2, kc = (tid & 3) * 16;
    f16x8_t w0 = *(const f16x8_t*)&t[nr][kc];
    f16x8_t w1 = *(const f16x8_t*)&t[nr][kc + 8];
    *(f16x8_t*)&dst[(size_t)(n0 + nr) * ld_dst + k0 + kc] = w0;
    *(f16x8_t*)&dst[(size_t)(n0 + nr) * ld_dst + k0 + kc + 8] = w1;
}

// ---------------- generic TN fp16 MFMA GEMM ----------------
// C[M][N] = A[M][K](row-major) x Bt[N][K];  64x64 tile, BK=64, 4 waves,
// double-buffered LDS, global_load_lds staging with XOR slot swizzle.
template<bool F16OUT>
__global__ __launch_bounds__(256) void gemm_f16t(
    const half_t* __restrict__ A, int lda, long long sA,
    const half_t* __restrict__ Bt, int ldb, long long sB,
    void* __restrict__ Cv, int ldc, long long sC, int K)
{
    A  += (size_t)blockIdx.z * sA;
    Bt += (size_t)blockIdx.z * sB;
    const int bm = blockIdx.y * 64, bn = blockIdx.x * 64;

    __shared__ __align__(16) char lds[2][16384];   // per buf: A 8KB | B 8KB

    const int tid = threadIdx.x, w = tid >> 6, lane = tid & 63;
    const int l15 = lane & 15, q = lane >> 4;
    const int wr = w >> 1, wc = w & 1;

    // staging addresses: wave w stages rows 16w..16w+15 of both tiles.
    // chunk c = p*64 + lane: row_local = c>>3, slotL = c&7, slotG = slotL ^ (row_local&7)
    const half_t* gA[2];
    const half_t* gB[2];
    #pragma unroll
    for (int p = 0; p < 2; p++) {
        int c = p * 64 + lane;
        int rl = c >> 3;
        int sg = (c & 7) ^ (rl & 7);
        gA[p] = A  + (size_t)(bm + w * 16 + rl) * lda + sg * 8;
        gB[p] = Bt + (size_t)(bn + w * 16 + rl) * ldb + sg * 8;
    }

    f32x4_t acc[2][2];
    #pragma unroll
    for (int i = 0; i < 2; i++)
        #pragma unroll
        for (int j = 0; j < 2; j++) acc[i][j] = (f32x4_t){0.f, 0.f, 0.f, 0.f};

    const int nsteps = K >> 6;

    // prologue
    {
        char* ab = lds[0];
        char* bb = ab + 8192;
        #pragma unroll
        for (int p = 0; p < 2; p++) {
            gload_lds16(gA[p], ab + w * 2048 + p * 1024);
            gload_lds16(gB[p], bb + w * 2048 + p * 1024);
        }
    }
    __syncthreads();

    int cur = 0;
    for (int s = 0; s < nsteps; s++) {
        if (s + 1 < nsteps) {
            int k0 = (s + 1) << 6;
            char* ab = lds[cur ^ 1];
            char* bb = ab + 8192;
            #pragma unroll
            for (int p = 0; p < 2; p++) {
                gload_lds16(gA[p] + k0, ab + w * 2048 + p * 1024);
                gload_lds16(gB[p] + k0, bb + w * 2048 + p * 1024);
            }
        }
        {
            const char* ab = lds[cur];
            const char* bb = ab + 8192;
            #pragma unroll
            for (int kk = 0; kk < 2; kk++) {
                f16x8_t av[2], bv[2];
                #pragma unroll
                for (int i = 0; i < 2; i++) {
                    int ra = wr * 32 + i * 16 + l15;
                    av[i] = *(const f16x8_t*)(ab + ra * 128 + (((kk * 4 + q) ^ (ra & 7)) * 16));
                    int rb = wc * 32 + i * 16 + l15;
                    bv[i] = *(const f16x8_t*)(bb + rb * 128 + (((kk * 4 + q) ^ (rb & 7)) * 16));
                }
                #pragma unroll
                for (int i = 0; i < 2; i++)
                    #pragma unroll
                    for (int j = 0; j < 2; j++)
                        acc[i][j] = MFMA_F16(av[i], bv[j], acc[i][j]);
            }
        }
        __syncthreads();
        cur ^= 1;
    }

    // epilogue: C row = bm + wr*32 + i*16 + q*4 + r, col = bn + wc*32 + j*16 + l15
    half_t* Ch = (half_t*)Cv + (F16OUT ? (size_t)blockIdx.z * sC : 0);
    float*  Cf = (float*)Cv  + (F16OUT ? 0 : (size_t)blockIdx.z * sC);
    #pragma unroll
    for (int i = 0; i < 2; i++)
        #pragma unroll
        for (int j = 0; j < 2; j++)
            #pragma unroll
            for (int r = 0; r < 4; r++) {
                size_t row = bm + wr * 32 + i * 16 + q * 4 + r;
                size_t col = bn + wc * 32 + j * 16 + l15;
                if (F16OUT) Ch[row * ldc + col] = (half_t)acc[i][j][r];
                else        Cf[row * ldc + col] = acc[i][j][r];
            }
}

// ---------------- copy q_pe tail (fp16) ----------------
__global__ void copy_pe16(const half_t* __restrict__ q, half_t* __restrict__ qf)
{
    int i = blockIdx.x * 256 + threadIdx.x;
    if (i >= M_DIM * H_DIM * D_R) return;
    int r = i & 63, mh = i >> 6;
    qf[(size_t)mh * D_ATT + D_KV_C + r] = q[(size_t)mh * (D_Q + D_R) + D_Q + r];
}

// ---------------- MFMA attention (fp16) ----------------
__global__ __launch_bounds__(256) void attn_mfma(
    const half_t* __restrict__ qf,    // [M*16][576] fp16
    const half_t* __restrict__ kvb,   // [4096][576] fp16
    const int* __restrict__ indices,  // [M][512]
    half_t* __restrict__ o)           // [M][16][512] fp16
{
    const int m = blockIdx.x;
    const int tid = threadIdx.x;
    const int w = tid >> 6, lane = tid & 63;
    const int l15 = lane & 15, q = lane >> 4;

    __shared__ __align__(16) char u_mem[16 * 513 * 4];       // scores f32 / V-tile swizzled
    __shared__ __align__(16) unsigned short p_s[16 * 512];   // P fp16 bits, swizzled rows
    __shared__ int idx_s[TOPK];

    float* s_s = (float*)u_mem;
    unsigned short* v_s = (unsigned short*)u_mem;

    for (int i = tid; i < TOPK; i += 256) idx_s[i] = indices[(size_t)m * TOPK + i];
    __syncthreads();

    // ---------- scores ----------
    int rows[8];
    #pragma unroll
    for (int tt = 0; tt < 8; tt++) rows[tt] = idx_s[(w * 8 + tt) * 16 + l15];

    f32x4_t acc[8];
    #pragma unroll
    for (int tt = 0; tt < 8; tt++) acc[tt] = (f32x4_t){0.f, 0.f, 0.f, 0.f};

    const half_t* qh = qf + ((size_t)m * 16 + l15) * D_ATT + q * 8;

    #pragma unroll 2
    for (int kk = 0; kk < 18; kk++) {
        f16x8_t ah = *(const f16x8_t*)(qh + kk * 32);
        #pragma unroll
        for (int tt = 0; tt < 8; tt++) {
            f16x8_t b = *(const f16x8_t*)(kvb + (size_t)rows[tt] * D_ATT + kk * 32 + q * 8);
            acc[tt] = MFMA_F16(ah, b, acc[tt]);
        }
    }

    const float scale = 1.0f / 24.0f;
    #pragma unroll
    for (int tt = 0; tt < 8; tt++) {
        int t = (w * 8 + tt) * 16 + l15;
        #pragma unroll
        for (int r = 0; r < 4; r++)
            s_s[(q * 4 + r) * 513 + t] = acc[tt][r] * scale;
    }
    __syncthreads();

    // ---------- softmax (fp32), emit P fp16 swizzled ----------
    {
        int h = tid >> 4, j = tid & 15;
        float mx = -1e30f;
        for (int t = j; t < TOPK; t += 16) mx = fmaxf(mx, s_s[h * 513 + t]);
        #pragma unroll
        for (int off = 8; off; off >>= 1) mx = fmaxf(mx, __shfl_xor(mx, off, 16));
        float sum = 0.f;
        for (int t = j; t < TOPK; t += 16) {
            float e = __expf(s_s[h * 513 + t] - mx);
            s_s[h * 513 + t] = e;
            sum += e;
        }
        #pragma unroll
        for (int off = 8; off; off >>= 1) sum += __shfl_xor(sum, off, 16);
        float inv = 1.0f / sum;
        for (int t = j; t < TOPK; t += 16) {
            union { half_t h; unsigned short u; } cv;
            cv.h = (half_t)(s_s[h * 513 + t] * inv);
            unsigned byte = ((unsigned)(t * 2)) ^ (((unsigned)(h & 7)) << 4);
            p_s[h * 512 + (byte >> 1)] = cv.u;
        }
    }
    __syncthreads();

    // ---------- PV ----------
    f32x4_t oacc[8];
    #pragma unroll
    for (int i = 0; i < 8; i++) oacc[i] = (f32x4_t){0.f, 0.f, 0.f, 0.f};

    const unsigned vbase = lds_addr32(v_s);
    const int jb = tid & 7, trow = tid >> 3;
    const unsigned swz_w = (((unsigned)(trow & 7)) << 4) ^ (((unsigned)((trow >> 3) & 3)) << 5);

    const int row1 = q * 8 + (l15 >> 2);
    const int row2 = row1 + 4;
    const unsigned sw1 = (((unsigned)(row1 & 7)) << 4) ^ (((unsigned)q & 3u) << 5);
    const unsigned sw2 = (((unsigned)(row2 & 7)) << 4) ^ (((unsigned)q & 3u) << 5);
    const unsigned cbyte = (unsigned)((l15 & 3) * 8);

    #pragma unroll 1
    for (int ct = 0; ct < 16; ct++) {
        int t0 = ct * 32;
        {
            int r = idx_s[t0 + trow];
            const half_t* src = kvb + (size_t)r * D_ATT + jb * 64;
            #pragma unroll
            for (int i = 0; i < 8; i++) {
                unsigned byte = ((unsigned)(jb * 128 + i * 16)) ^ swz_w;
                *(f16x8_t*)((char*)v_s + trow * 1024 + byte) = *(const f16x8_t*)(src + i * 8);
            }
        }
        __syncthreads();

        f16x8_t pa;
        {
            unsigned pbyte = ((unsigned)(t0 * 2 + q * 16)) ^ (((unsigned)(l15 & 7)) << 4);
            pa = *(const f16x8_t*)((const char*)p_s + l15 * 1024 + pbyte);
        }

        u32x2_t blo[8], bhi[8];
        #pragma unroll
        for (int i = 0; i < 8; i++) {
            unsigned c2 = ((unsigned)(((w * 8 + i) * 16) * 2)) + cbyte;
            unsigned a1 = vbase + (unsigned)row1 * 1024u + (c2 ^ sw1);
            unsigned a2 = vbase + (unsigned)row2 * 1024u + (c2 ^ sw2);
            asm volatile("ds_read_b64_tr_b16 %0, %1 offset:0" : "=v"(blo[i]) : "v"(a1) : "memory");
            asm volatile("ds_read_b64_tr_b16 %0, %1 offset:0" : "=v"(bhi[i]) : "v"(a2) : "memory");
        }
        asm volatile("s_waitcnt lgkmcnt(0)" ::: "memory");
        __builtin_amdgcn_sched_barrier(0);

        #pragma unroll
        for (int i = 0; i < 8; i++) {
            union { f16x8_t s; struct { u32x2_t lo, hi; } u; } f;
            f.u.lo = blo[i]; f.u.hi = bhi[i];
            oacc[i] = MFMA_F16(pa, f.s, oacc[i]);
        }
        __syncthreads();
    }

    // write o (fp16): row = head h = q*4+r, col c
    half_t* ob = o + (size_t)m * (H_DIM * D_KV_C);
    #pragma unroll
    for (int i = 0; i < 8; i++) {
        int c = (w * 8 + i) * 16 + l15;
        #pragma unroll
        for (int r = 0; r < 4; r++)
            ob[(size_t)(q * 4 + r) * D_KV_C + c] = (half_t)oacc[i][r];
    }
}

// ---------------- launch ----------------
extern "C" void kernel_launch(void* const* d_in, const int* in_sizes, int n_in,
                              void* d_out, int out_size, void* d_ws, size_t ws_size,
                              hipStream_t stream)
{
    const float* x        = (const float*)d_in[0];
    const float* W_cqkv   = (const float*)d_in[1];
    const float* W_uq     = (const float*)d_in[2];
    const float* W_qk     = (const float*)d_in[3];
    const float* kv_cache = (const float*)d_in[4];
    const float* W_o1     = (const float*)d_in[5];
    const float* W_oproj  = (const float*)d_in[6];
    const int*   indices  = (const int*)d_in[7];
    float* out = (float*)d_out;

    // workspace layout (half_t units) with overlays:
    half_t* wsh = (half_t*)d_ws;
    half_t* Wcqkv_t = wsh;                 // 11,010,048  [1536][7168]
    half_t* o16     = wsh;                 // 4,194,304   (after gemm1)
    half_t* Wuq_t   = wsh + 11010048;      // 4,718,592   [3072][1536]
    half_t* qf16    = wsh + 11010048;      // 4,718,592   (after gemm2) [512*16][576]
    half_t* Wqk_t   = wsh + 15728640;      // 1,048,576   [16][512][128]
    half_t* Wo1_t   = wsh + 16777216;      // 1,048,576   [16][128][512]
    half_t* Wop_t   = wsh + 17825792;      // 14,680,064  [7168][2048]
    half_t* x16     = wsh + 32505856;      // 3,670,016   [512][7168]
    half_t* o2_16   = wsh + 32505856;      // 1,048,576   (after gemm1) [512][2048]
    half_t* qc16    = wsh + 36175872;      // 786,432     [512][1536]
    half_t* q16     = wsh + 36962304;      // 1,572,864   [512][3072]
    half_t* kv16    = wsh + 38535168;      // 2,359,296   [4096][576]
    // high-water: 40,894,464 halves = 81.8 MB

    // ---- conversions ----
    cvt_f16<<<(M_DIM * HID / 8 + 255) / 256, 256, 0, stream>>>(x, x16, M_DIM * HID / 8);
    cvt_f16<<<(S_KV * D_ATT / 8 + 255) / 256, 256, 0, stream>>>(kv_cache, kv16, S_KV * D_ATT / 8);
    // W_cqkv[:, 512:2048] -> [1536][7168]
    cvt_t<<<dim3(D_Q_C / 64, HID / 64, 1), 256, 0, stream>>>(
        W_cqkv + D_KV_C, D_KV_C + D_Q_C + D_R, 0, Wcqkv_t, HID, 0);
    // W_uq -> [3072][1536]
    cvt_t<<<dim3(3072 / 64, D_Q_C / 64, 1), 256, 0, stream>>>(
        W_uq, 3072, 0, Wuq_t, D_Q_C, 0);
    // W_qk[h] [128][512] -> [512][128]
    cvt_t<<<dim3(D_KV_C / 64, D_Q / 64, H_DIM), 256, 0, stream>>>(
        W_qk, D_KV_C, D_Q * D_KV_C, Wqk_t, D_Q, D_Q * D_KV_C);
    // W_o1[h] [512][128] -> [128][512]
    cvt_t<<<dim3(D_KV / 64, D_KV_C / 64, H_DIM), 256, 0, stream>>>(
        W_o1, D_KV, D_KV_C * D_KV, Wo1_t, D_KV_C, D_KV_C * D_KV);
    // W_oproj [2048][7168] -> [7168][2048]
    cvt_t<<<dim3(HID / 64, 2048 / 64, 1), 256, 0, stream>>>(
        W_oproj, HID, 0, Wop_t, 2048, 0);

    // ---- GEMM chain ----
    // 1) q_c16 = x16 @ Wcqkv_t^T   (512x1536, K=7168)
    gemm_f16t<true><<<dim3(D_Q_C / 64, M_DIM / 64, 1), 256, 0, stream>>>(
        x16, HID, 0, Wcqkv_t, HID, 0, qc16, D_Q_C, 0, HID);

    // 2) q16 = qc16 @ Wuq_t^T      (512x3072, K=1536)
    gemm_f16t<true><<<dim3(3072 / 64, M_DIM / 64, 1), 256, 0, stream>>>(
        qc16, D_Q_C, 0, Wuq_t, D_Q_C, 0, q16, 3072, 0, D_Q_C);

    // 2b) q_pe tail into qf16
    copy_pe16<<<(M_DIM * H_DIM * D_R + 255) / 256, 256, 0, stream>>>(q16, qf16);

    // 3) qf16[:, h, :512] = q_nope[:,h,:] @ Wqk_t[h]^T  (512x512, K=128, z=16)
    gemm_f16t<true><<<dim3(D_KV_C / 64, M_DIM / 64, H_DIM), 256, 0, stream>>>(
        q16, 3072, D_Q + D_R, Wqk_t, D_Q, (long long)D_Q * D_KV_C,
        qf16, H_DIM * D_ATT, D_ATT, D_Q);

    // 4) attention
    attn_mfma<<<M_DIM, 256, 0, stream>>>(qf16, kv16, indices, o16);

    // 5) o2 = o[:,h,:] @ Wo1_t[h]^T  (512x128, K=512, z=16)
    gemm_f16t<true><<<dim3(D_KV / 64, M_DIM / 64, H_DIM), 256, 0, stream>>>(
        o16, H_DIM * D_KV_C, D_KV_C, Wo1_t, D_KV_C, (long long)D_KV_C * D_KV,
        o2_16, H_DIM * D_KV, D_KV, D_KV_C);

    // 6) out = o2 @ Wop_t^T  (512x7168, K=2048) fp32 out
    gemm_f16t<false><<<dim3(HID / 64, M_DIM / 64, 1), 256, 0, stream>>>(
        o2_16, H_DIM * D_KV, 0, Wop_t, 2048, 0, out, HID, 0, H_DIM * D_KV);
}

// Round 4
// 221.377 us; speedup vs baseline: 9.3299x; 1.1809x over previous
//
#include <hip/hip_runtime.h>
#include <hip/hip_bf16.h>

#define M_DIM 512
#define HID 7168
#define D_KV_C 512
#define D_Q_C 1536
#define D_R 64
#define D_Q 128
#define D_KV 128
#define H_DIM 16
#define S_KV 4096
#define TOPK 512
#define D_ATT 576

typedef _Float16 half_t;
typedef __attribute__((ext_vector_type(8))) _Float16 f16x8_t;
typedef __attribute__((ext_vector_type(4))) float f32x4_t;
typedef __attribute__((ext_vector_type(2))) unsigned int u32x2_t;

#define MFMA_F16(a, b, c) __builtin_amdgcn_mfma_f32_16x16x32_f16((a), (b), (c), 0, 0, 0)

__device__ __forceinline__ unsigned lds_addr32(const void* p) {
    return (unsigned)(unsigned long long)(const __attribute__((address_space(3))) char*)p;
}

typedef const __attribute__((address_space(1))) unsigned int* gptr_t;
typedef __attribute__((address_space(3))) unsigned int* lptr_t;
__device__ __forceinline__ void gload_lds16(const void* g, void* l) {
    __builtin_amdgcn_global_load_lds((gptr_t)g, (lptr_t)l, 16, 0, 0);
}

// ---------------- elementwise fp32 -> fp16 ----------------
__global__ __launch_bounds__(256) void cvt_f16(const float* __restrict__ src,
                                               half_t* __restrict__ dst, int n8)
{
    int i = blockIdx.x * 256 + threadIdx.x;
    if (i >= n8) return;
    const float4* s = (const float4*)src + (size_t)i * 2;
    float4 a = s[0], b = s[1];
    f16x8_t o;
    o[0] = (half_t)a.x; o[1] = (half_t)a.y; o[2] = (half_t)a.z; o[3] = (half_t)a.w;
    o[4] = (half_t)b.x; o[5] = (half_t)b.y; o[6] = (half_t)b.z; o[7] = (half_t)b.w;
    *(f16x8_t*)(dst + (size_t)i * 8) = o;
}

// ---------------- sum NS fp32 slices -> fp16 ----------------
template<int NS>
__global__ __launch_bounds__(256) void cvt_sum(const float* __restrict__ src, long long slice,
                                               half_t* __restrict__ dst, int n8)
{
    int i = blockIdx.x * 256 + threadIdx.x;
    if (i >= n8) return;
    float a[8] = {};
    #pragma unroll
    for (int s = 0; s < NS; s++) {
        const float4* p = (const float4*)(src + (size_t)s * slice) + (size_t)i * 2;
        float4 u = p[0], v = p[1];
        a[0] += u.x; a[1] += u.y; a[2] += u.z; a[3] += u.w;
        a[4] += v.x; a[5] += v.y; a[6] += v.z; a[7] += v.w;
    }
    f16x8_t o;
    #pragma unroll
    for (int j = 0; j < 8; j++) o[j] = (half_t)a[j];
    *(f16x8_t*)(dst + (size_t)i * 8) = o;
}

// sum 2 slices of q (512x3072) -> q16, scatter pe cols into qf16 tail
__global__ __launch_bounds__(256) void cvt_sum_q(const float* __restrict__ src, long long slice,
                                                 half_t* __restrict__ q16, half_t* __restrict__ qf)
{
    int i = blockIdx.x * 256 + threadIdx.x;
    if (i >= M_DIM * 3072 / 8) return;
    float a[8] = {};
    #pragma unroll
    for (int s = 0; s < 2; s++) {
        const float4* p = (const float4*)(src + (size_t)s * slice) + (size_t)i * 2;
        float4 u = p[0], v = p[1];
        a[0] += u.x; a[1] += u.y; a[2] += u.z; a[3] += u.w;
        a[4] += v.x; a[5] += v.y; a[6] += v.z; a[7] += v.w;
    }
    f16x8_t o;
    #pragma unroll
    for (int j = 0; j < 8; j++) o[j] = (half_t)a[j];
    *(f16x8_t*)(q16 + (size_t)i * 8) = o;
    int col = (i * 8) % 3072;
    int c = col % 192;                 // within-head col; blocks of 8 never straddle
    if (c >= 128) {
        int row = (i * 8) / 3072, h = col / 192;
        int mh = row * 16 + h;
        *(f16x8_t*)(qf + (size_t)mh * D_ATT + D_KV_C + (c - 128)) = o;
    }
}

// ---------------- transpose-convert fp32 [K][ld] -> fp16 [N][K] ----------------
__global__ __launch_bounds__(256) void cvt_t(
    const float* __restrict__ src, int ld_src, long long sS,
    half_t* __restrict__ dst, int ld_dst, long long sD)
{
    src += (size_t)blockIdx.z * sS;
    dst += (size_t)blockIdx.z * sD;
    int k0 = blockIdx.y * 64, n0 = blockIdx.x * 64;
    __shared__ half_t t[64][80];
    int tid = threadIdx.x;
    int kr = tid >> 4, nc = (tid & 15) * 4;
    #pragma unroll
    for (int i = 0; i < 4; i++) {
        float4 v = *(const float4*)&src[(size_t)(k0 + kr + i * 16) * ld_src + n0 + nc];
        t[nc + 0][kr + i * 16] = (half_t)v.x;
        t[nc + 1][kr + i * 16] = (half_t)v.y;
        t[nc + 2][kr + i * 16] = (half_t)v.z;
        t[nc + 3][kr + i * 16] = (half_t)v.w;
    }
    __syncthreads();
    int nr = tid >> 2, kc = (tid & 3) * 16;
    f16x8_t w0 = *(const f16x8_t*)&t[nr][kc];
    f16x8_t w1 = *(const f16x8_t*)&t[nr][kc + 8];
    *(f16x8_t*)&dst[(size_t)(n0 + nr) * ld_dst + k0 + kc] = w0;
    *(f16x8_t*)&dst[(size_t)(n0 + nr) * ld_dst + k0 + kc + 8] = w1;
}

// ---------------- generic TN fp16 MFMA GEMM ----------------
// C[M][N] = A[M][K] x Bt[N][K]; 64x64 tile, BK=64, 4 waves, dbuf LDS,
// global_load_lds staging with XOR slot swizzle. z-dim: batch OR K-split
// (sA/sB = per-z K-offset in elements, sC = per-z C-offset).
template<bool F16OUT>
__global__ __launch_bounds__(256) void gemm_f16t(
    const half_t* __restrict__ A, int lda, long long sA,
    const half_t* __restrict__ Bt, int ldb, long long sB,
    void* __restrict__ Cv, int ldc, long long sC, int K)
{
    A  += (size_t)blockIdx.z * sA;
    Bt += (size_t)blockIdx.z * sB;
    const int bm = blockIdx.y * 64, bn = blockIdx.x * 64;

    __shared__ __align__(16) char lds[2][16384];

    const int tid = threadIdx.x, w = tid >> 6, lane = tid & 63;
    const int l15 = lane & 15, q = lane >> 4;
    const int wr = w >> 1, wc = w & 1;

    const half_t* gA[2];
    const half_t* gB[2];
    #pragma unroll
    for (int p = 0; p < 2; p++) {
        int c = p * 64 + lane;
        int rl = c >> 3;
        int sg = (c & 7) ^ (rl & 7);
        gA[p] = A  + (size_t)(bm + w * 16 + rl) * lda + sg * 8;
        gB[p] = Bt + (size_t)(bn + w * 16 + rl) * ldb + sg * 8;
    }

    f32x4_t acc[2][2];
    #pragma unroll
    for (int i = 0; i < 2; i++)
        #pragma unroll
        for (int j = 0; j < 2; j++) acc[i][j] = (f32x4_t){0.f, 0.f, 0.f, 0.f};

    const int nsteps = K >> 6;

    {
        char* ab = lds[0];
        char* bb = ab + 8192;
        #pragma unroll
        for (int p = 0; p < 2; p++) {
            gload_lds16(gA[p], ab + w * 2048 + p * 1024);
            gload_lds16(gB[p], bb + w * 2048 + p * 1024);
        }
    }
    __syncthreads();

    int cur = 0;
    for (int s = 0; s < nsteps; s++) {
        if (s + 1 < nsteps) {
            int k0 = (s + 1) << 6;
            char* ab = lds[cur ^ 1];
            char* bb = ab + 8192;
            #pragma unroll
            for (int p = 0; p < 2; p++) {
                gload_lds16(gA[p] + k0, ab + w * 2048 + p * 1024);
                gload_lds16(gB[p] + k0, bb + w * 2048 + p * 1024);
            }
        }
        {
            const char* ab = lds[cur];
            const char* bb = ab + 8192;
            #pragma unroll
            for (int kk = 0; kk < 2; kk++) {
                f16x8_t av[2], bv[2];
                #pragma unroll
                for (int i = 0; i < 2; i++) {
                    int ra = wr * 32 + i * 16 + l15;
                    av[i] = *(const f16x8_t*)(ab + ra * 128 + (((kk * 4 + q) ^ (ra & 7)) * 16));
                    int rb = wc * 32 + i * 16 + l15;
                    bv[i] = *(const f16x8_t*)(bb + rb * 128 + (((kk * 4 + q) ^ (rb & 7)) * 16));
                }
                #pragma unroll
                for (int i = 0; i < 2; i++)
                    #pragma unroll
                    for (int j = 0; j < 2; j++)
                        acc[i][j] = MFMA_F16(av[i], bv[j], acc[i][j]);
            }
        }
        __syncthreads();
        cur ^= 1;
    }

    half_t* Ch = (half_t*)Cv + (F16OUT ? (size_t)blockIdx.z * sC : 0);
    float*  Cf = (float*)Cv  + (F16OUT ? 0 : (size_t)blockIdx.z * sC);
    #pragma unroll
    for (int i = 0; i < 2; i++)
        #pragma unroll
        for (int j = 0; j < 2; j++)
            #pragma unroll
            for (int r = 0; r < 4; r++) {
                size_t row = bm + wr * 32 + i * 16 + q * 4 + r;
                size_t col = bn + wc * 32 + j * 16 + l15;
                if (F16OUT) Ch[row * ldc + col] = (half_t)acc[i][j][r];
                else        Cf[row * ldc + col] = acc[i][j][r];
            }
}

// ---------------- MFMA attention (fp16), async-split PV pipeline ----------------
__global__ __launch_bounds__(256) void attn_mfma(
    const half_t* __restrict__ qf,    // [M*16][576]
    const half_t* __restrict__ kvb,   // [4096][576]
    const int* __restrict__ indices,  // [M][512]
    half_t* __restrict__ o)           // [M][16][512]
{
    const int m = blockIdx.x;
    const int tid = threadIdx.x;
    const int w = tid >> 6, lane = tid & 63;
    const int l15 = lane & 15, q = lane >> 4;

    __shared__ __align__(16) char u_mem[16 * 513 * 4];       // scores f32 / V-tile swizzled
    __shared__ __align__(16) unsigned short p_s[16 * 512];   // P fp16 bits, swizzled rows
    __shared__ int idx_s[TOPK];

    float* s_s = (float*)u_mem;
    unsigned short* v_s = (unsigned short*)u_mem;

    for (int i = tid; i < TOPK; i += 256) idx_s[i] = indices[(size_t)m * TOPK + i];
    __syncthreads();

    // ---------- scores ----------
    int rows[8];
    #pragma unroll
    for (int tt = 0; tt < 8; tt++) rows[tt] = idx_s[(w * 8 + tt) * 16 + l15];

    f32x4_t acc[8];
    #pragma unroll
    for (int tt = 0; tt < 8; tt++) acc[tt] = (f32x4_t){0.f, 0.f, 0.f, 0.f};

    const half_t* qh = qf + ((size_t)m * 16 + l15) * D_ATT + q * 8;

    #pragma unroll 2
    for (int kk = 0; kk < 18; kk++) {
        f16x8_t ah = *(const f16x8_t*)(qh + kk * 32);
        #pragma unroll
        for (int tt = 0; tt < 8; tt++) {
            f16x8_t b = *(const f16x8_t*)(kvb + (size_t)rows[tt] * D_ATT + kk * 32 + q * 8);
            acc[tt] = MFMA_F16(ah, b, acc[tt]);
        }
    }

    const float scale = 1.0f / 24.0f;
    #pragma unroll
    for (int tt = 0; tt < 8; tt++) {
        int t = (w * 8 + tt) * 16 + l15;
        #pragma unroll
        for (int r = 0; r < 4; r++)
            s_s[(q * 4 + r) * 513 + t] = acc[tt][r] * scale;
    }
    __syncthreads();

    // ---------- softmax (fp32), emit P fp16 swizzled ----------
    {
        int h = tid >> 4, j = tid & 15;
        float mx = -1e30f;
        for (int t = j; t < TOPK; t += 16) mx = fmaxf(mx, s_s[h * 513 + t]);
        #pragma unroll
        for (int off = 8; off; off >>= 1) mx = fmaxf(mx, __shfl_xor(mx, off, 16));
        float sum = 0.f;
        for (int t = j; t < TOPK; t += 16) {
            float e = __expf(s_s[h * 513 + t] - mx);
            s_s[h * 513 + t] = e;
            sum += e;
        }
        #pragma unroll
        for (int off = 8; off; off >>= 1) sum += __shfl_xor(sum, off, 16);
        float inv = 1.0f / sum;
        for (int t = j; t < TOPK; t += 16) {
            union { half_t h; unsigned short u; } cv;
            cv.h = (half_t)(s_s[h * 513 + t] * inv);
            unsigned byte = ((unsigned)(t * 2)) ^ (((unsigned)(h & 7)) << 4);
            p_s[h * 512 + (byte >> 1)] = cv.u;
        }
    }
    __syncthreads();

    // ---------- PV (async-split double pipeline) ----------
    f32x4_t oacc[8];
    #pragma unroll
    for (int i = 0; i < 8; i++) oacc[i] = (f32x4_t){0.f, 0.f, 0.f, 0.f};

    const unsigned vbase = lds_addr32(v_s);
    const int jb = tid & 7, trow = tid >> 3;
    const unsigned swz_w = (((unsigned)(trow & 7)) << 4) ^ (((unsigned)((trow >> 3) & 3)) << 5);

    // preload this thread's stage-row index for each of the 16 tiles
    int rstage[16];
    #pragma unroll
    for (int ct = 0; ct < 16; ct++) rstage[ct] = idx_s[ct * 32 + trow];

    const int row1 = q * 8 + (l15 >> 2);
    const int row2 = row1 + 4;
    const unsigned sw1 = (((unsigned)(row1 & 7)) << 4) ^ (((unsigned)q & 3u) << 5);
    const unsigned sw2 = (((unsigned)(row2 & 7)) << 4) ^ (((unsigned)q & 3u) << 5);
    const unsigned cbyte = (unsigned)((l15 & 3) * 8);

    // prologue: stage tile 0
    {
        const half_t* src = kvb + (size_t)rstage[0] * D_ATT + jb * 64;
        f16x8_t tmp[8];
        #pragma unroll
        for (int i = 0; i < 8; i++) tmp[i] = *(const f16x8_t*)(src + i * 8);
        #pragma unroll
        for (int i = 0; i < 8; i++) {
            unsigned byte = ((unsigned)(jb * 128 + i * 16)) ^ swz_w;
            *(f16x8_t*)((char*)v_s + trow * 1024 + byte) = tmp[i];
        }
    }
    __syncthreads();

    #pragma unroll 1
    for (int ct = 0; ct < 16; ct++) {
        int t0 = ct * 32;

        // issue next tile's gather loads early (latency hides under MFMA phase)
        f16x8_t nxt[8];
        if (ct < 15) {
            const half_t* src = kvb + (size_t)rstage[ct + 1] * D_ATT + jb * 64;
            #pragma unroll
            for (int i = 0; i < 8; i++) nxt[i] = *(const f16x8_t*)(src + i * 8);
        }

        // A-frag from swizzled p_s
        f16x8_t pa;
        {
            unsigned pbyte = ((unsigned)(t0 * 2 + q * 16)) ^ (((unsigned)(l15 & 7)) << 4);
            pa = *(const f16x8_t*)((const char*)p_s + l15 * 1024 + pbyte);
        }

        // B-frags via hardware transpose reads
        u32x2_t blo[8], bhi[8];
        #pragma unroll
        for (int i = 0; i < 8; i++) {
            unsigned c2 = ((unsigned)(((w * 8 + i) * 16) * 2)) + cbyte;
            unsigned a1 = vbase + (unsigned)row1 * 1024u + (c2 ^ sw1);
            unsigned a2 = vbase + (unsigned)row2 * 1024u + (c2 ^ sw2);
            asm volatile("ds_read_b64_tr_b16 %0, %1 offset:0" : "=v"(blo[i]) : "v"(a1) : "memory");
            asm volatile("ds_read_b64_tr_b16 %0, %1 offset:0" : "=v"(bhi[i]) : "v"(a2) : "memory");
        }
        asm volatile("s_waitcnt lgkmcnt(0)" ::: "memory");
        __builtin_amdgcn_sched_barrier(0);

        __builtin_amdgcn_s_setprio(1);
        #pragma unroll
        for (int i = 0; i < 8; i++) {
            union { f16x8_t s; struct { u32x2_t lo, hi; } u; } f;
            f.u.lo = blo[i]; f.u.hi = bhi[i];
            oacc[i] = MFMA_F16(pa, f.s, oacc[i]);
        }
        __builtin_amdgcn_s_setprio(0);

        __syncthreads();   // all waves done reading v_s

        if (ct < 15) {
            #pragma unroll
            for (int i = 0; i < 8; i++) {
                unsigned byte = ((unsigned)(jb * 128 + i * 16)) ^ swz_w;
                *(f16x8_t*)((char*)v_s + trow * 1024 + byte) = nxt[i];
            }
        }
        __syncthreads();   // next tile staged
    }

    half_t* ob = o + (size_t)m * (H_DIM * D_KV_C);
    #pragma unroll
    for (int i = 0; i < 8; i++) {
        int c = (w * 8 + i) * 16 + l15;
        #pragma unroll
        for (int r = 0; r < 4; r++)
            ob[(size_t)(q * 4 + r) * D_KV_C + c] = (half_t)oacc[i][r];
    }
}

// ---------------- launch ----------------
extern "C" void kernel_launch(void* const* d_in, const int* in_sizes, int n_in,
                              void* d_out, int out_size, void* d_ws, size_t ws_size,
                              hipStream_t stream)
{
    const float* x        = (const float*)d_in[0];
    const float* W_cqkv   = (const float*)d_in[1];
    const float* W_uq     = (const float*)d_in[2];
    const float* W_qk     = (const float*)d_in[3];
    const float* kv_cache = (const float*)d_in[4];
    const float* W_o1     = (const float*)d_in[5];
    const float* W_oproj  = (const float*)d_in[6];
    const int*   indices  = (const int*)d_in[7];
    float* out = (float*)d_out;

    // workspace layout (half_t units), lifetime-overlaid; peak 44.83M halves = 89.7MB
    half_t* wsh = (half_t*)d_ws;
    half_t* Wcqkv_t = wsh;                      // [0, 11010048)
    half_t* qc16    = wsh;                      //   overlay after gemm1: [0, 786432)
    half_t* q32h    = wsh + 786432;             //   overlay: [786432, 7077888) fp32 x2 slices
    half_t* q16     = wsh + 7077888;            //   overlay: [7077888, 8650752)
    half_t* x16     = wsh + 11010048;           // [11010048, 14680064)
    half_t* o2_16   = wsh + 11010048;           //   overlay after gemm1
    half_t* Wuq_t   = wsh + 14680064;           // [14680064, 19398656)
    half_t* o16     = wsh + 14680064;           //   overlay after gemm2
    half_t* Wqk_t   = wsh + 19398656;           // [19398656, 20447232)
    half_t* Wo1_t   = wsh + 20447232;           // [20447232, 21495808)
    half_t* Wop_t   = wsh + 21495808;           // [21495808, 36175872)
    half_t* kv16    = wsh + 36175872;           // [36175872, 38535168)
    half_t* qc32h   = wsh + 38535168;           // [38535168, 44826624) fp32 x4 slices
    half_t* qf16    = wsh + 38535168;           //   overlay after cvt_sum1: [.., 43253760)
    float* qc32 = (float*)qc32h;
    float* q32  = (float*)q32h;

    // ---- conversions (depend only on inputs) ----
    cvt_f16<<<(M_DIM * HID / 8 + 255) / 256, 256, 0, stream>>>(x, x16, M_DIM * HID / 8);
    cvt_f16<<<(S_KV * D_ATT / 8 + 255) / 256, 256, 0, stream>>>(kv_cache, kv16, S_KV * D_ATT / 8);
    cvt_t<<<dim3(D_Q_C / 64, HID / 64, 1), 256, 0, stream>>>(
        W_cqkv + D_KV_C, D_KV_C + D_Q_C + D_R, 0, Wcqkv_t, HID, 0);
    cvt_t<<<dim3(3072 / 64, D_Q_C / 64, 1), 256, 0, stream>>>(
        W_uq, 3072, 0, Wuq_t, D_Q_C, 0);
    cvt_t<<<dim3(D_KV_C / 64, D_Q / 64, H_DIM), 256, 0, stream>>>(
        W_qk, D_KV_C, D_Q * D_KV_C, Wqk_t, D_Q, D_Q * D_KV_C);
    cvt_t<<<dim3(D_KV / 64, D_KV_C / 64, H_DIM), 256, 0, stream>>>(
        W_o1, D_KV, D_KV_C * D_KV, Wo1_t, D_KV_C, D_KV_C * D_KV);
    cvt_t<<<dim3(HID / 64, 2048 / 64, 1), 256, 0, stream>>>(
        W_oproj, HID, 0, Wop_t, 2048, 0);

    // ---- GEMM chain ----
    // 1) qc32 slices = x16 @ Wcqkv_t^T, split-K x4 (K=7168 -> 4x1792)
    gemm_f16t<false><<<dim3(D_Q_C / 64, M_DIM / 64, 4), 256, 0, stream>>>(
        x16, HID, 1792, Wcqkv_t, HID, 1792, qc32, D_Q_C, (long long)M_DIM * D_Q_C, 1792);
    cvt_sum<4><<<(M_DIM * D_Q_C / 8 + 255) / 256, 256, 0, stream>>>(
        qc32, (long long)M_DIM * D_Q_C, qc16, M_DIM * D_Q_C / 8);

    // 2) q32 slices = qc16 @ Wuq_t^T, split-K x2 (K=1536 -> 2x768)
    gemm_f16t<false><<<dim3(3072 / 64, M_DIM / 64, 2), 256, 0, stream>>>(
        qc16, D_Q_C, 768, Wuq_t, D_Q_C, 768, q32, 3072, (long long)M_DIM * 3072, 768);
    cvt_sum_q<<<(M_DIM * 3072 / 8 + 255) / 256, 256, 0, stream>>>(
        q32, (long long)M_DIM * 3072, q16, qf16);

    // 3) qf16[:, h, :512] = q_nope[:,h,:] @ Wqk_t[h]^T (batched z=16, K=128)
    gemm_f16t<true><<<dim3(D_KV_C / 64, M_DIM / 64, H_DIM), 256, 0, stream>>>(
        q16, 3072, D_Q + D_R, Wqk_t, D_Q, (long long)D_Q * D_KV_C,
        qf16, H_DIM * D_ATT, D_ATT, D_Q);

    // 4) attention
    attn_mfma<<<M_DIM, 256, 0, stream>>>(qf16, kv16, indices, o16);

    // 5) o2 = o[:,h,:] @ Wo1_t[h]^T (batched z=16, K=512)
    gemm_f16t<true><<<dim3(D_KV / 64, M_DIM / 64, H_DIM), 256, 0, stream>>>(
        o16, H_DIM * D_KV_C, D_KV_C, Wo1_t, D_KV_C, (long long)D_KV_C * D_KV,
        o2_16, H_DIM * D_KV, D_KV, D_KV_C);

    // 6) out = o2 @ Wop_t^T (K=2048), fp32 out
    gemm_f16t<false><<<dim3(HID / 64, M_DIM / 64, 1), 256, 0, stream>>>(
        o2_16, H_DIM * D_KV, 0, Wop_t, 2048, 0, out, HID, 0, H_DIM * D_KV);
}